// Round 6
// baseline (5659.237 us; speedup 1.0000x reference)
//
#include <hip/hip_runtime.h>
#include <hip/hip_bf16.h>
#include <cstdint>
#include <cstddef>

typedef __bf16 bf16;
typedef __bf16 bf16x2 __attribute__((ext_vector_type(2)));
typedef __bf16 bf16x4 __attribute__((ext_vector_type(4)));
typedef __bf16 bf16x8 __attribute__((ext_vector_type(8)));
typedef float f32x4 __attribute__((ext_vector_type(4)));

static_assert(sizeof(bf16x8) == 16, "bf16x8 must be 16B");

#define NE 16384   // E
#define ND 1024    // D
#define NA 512     // A
#define NM 2048    // M
#define NH 3
#define NRES 3

// ---------------------------------------------------------------------------
// async global->LDS, 16B per lane (wave-uniform LDS base + lane*16 implicit)
__device__ __forceinline__ void async_ld16(const bf16* g, bf16* l) {
  __builtin_amdgcn_global_load_lds(
      (__attribute__((address_space(1))) void*)(void*)g,
      (__attribute__((address_space(3))) void*)(void*)l, 16, 0, 0);
}

template <int N>
__device__ __forceinline__ void vm_wait() {
  asm volatile("s_waitcnt vmcnt(%0)" ::"n"(N) : "memory");
}
__device__ __forceinline__ void lgkm0() {
  asm volatile("s_waitcnt lgkmcnt(0)" ::: "memory");
}
__device__ __forceinline__ void bar() {
  asm volatile("s_barrier" ::: "memory");
}

// ---------------------------------------------------------------------------
// 256x256-tile SINGLE-BARRIER-PER-K-TILE bf16 GEMM: C = A[M,K] @ B^T[N,K],
// fp32 accum via v_mfma_f32_16x16x32_bf16. 512 threads = 8 waves (2M x 4N),
// each wave owns 128x64 of C (acc[8][4] f32x4). K consumed in 64-wide tiles.
//
// R6 structure: R2-R5's 8-barriers/K-tile forced the CU's single resident
// block (128 KiB LDS -> 1 block/CU) to alternate LDS and MFMA segments
// (~2480 MFMA + ~2800 LDS + ~1200 barrier cyc serialized = 6500/tile, 32%
// MfmaUtil). Since tile T's fragments are read into REGISTERS during T-1,
// each K-tile is now ONE inter-barrier segment:
//   [ stage(T+2 -> buf_{T&1})                       (8 global_load_lds)
//     64 MFMAs (8 groups of 8, Gray quadrant order)
//       interleaved with 24 ds_read_b128 refilling F(T+1) from buf_{(T+1)&1}
//       (in-place refill: each fa/fb piece rewritten right after its last
//        consumer group -> register deps order reads behind MFMAs)
//     lgkmcnt(0); vmcnt(0); s_barrier ]
// Hazard ledger:
//  - stage(T+2->buf_T): last reads of buf_T were F(T) reads during T-1,
//    drained by T-1's lgkmcnt(0) BEFORE its barrier -> >=1 barrier gap.
//  - F(T+1) reads: buf_{T+1} staged at (T-1)-start, retired by (T-1)-end
//    vmcnt(0) + barrier (cross-wave visibility order: wait THEN barrier).
//  - tail waits only touch tile-old ops (issued a full tile ago, ~3000+ cyc
//    >> 900-cyc HBM miss) -> no real drain stall; the T4 "window" is kept
//    via stage-at-tile-start, not via a nonzero count.
//
// LDS per matrix: [2 bufs][2 units][128 rows][64 cols] bf16 (64 KiB), total
// 128 KiB. Unit u holds global rows (lr>>6)*128 + u*64 + (lr&63). Chunk
// swizzle: logical chunk cc of row r stored at slot cc ^ (r&7); global source
// pre-swizzled so global_load_lds dest stays linear.
//
// C-column mapping: n = (wn>>1)*128 + NQ*64 + (wn&1)*32 + j*16 + l15
//
// MODE 0: C_bf16 = acc + bias[n]
// MODE 1: C_bf16 = addb[m,n] + relu(acc + bias[n])        (residual, in-place)
// MODE 2: C_bf16[m, coloff+n] = acc + bias[n] + addb[m,n] (head_out -> cat)
// MODE 3: C_f32[m,n] += acc                               (final += Q-K)

#define LDA4(SRC, MQ, KS)                                                     \
  {                                                                           \
    const int ab_ = ((SRC)*2 + (MQ)) * 8192 + aOff;                           \
    const int co_ = (c0 ^ ((KS) << 2)) * 8;                                   \
    _Pragma("unroll") for (int i = 0; i < 4; ++i)                             \
        fa[MQ][KS][i] = *(const bf16x8*)&lA[ab_ + i * 1024 + co_];            \
  }

#define LDB2(SRC, NQ, KS)                                                     \
  {                                                                           \
    const int bb_ = ((SRC)*2 + (NQ)) * 8192 + bOff;                           \
    const int co_ = (c0 ^ ((KS) << 2)) * 8;                                   \
    _Pragma("unroll") for (int j = 0; j < 2; ++j)                             \
        fb[NQ][KS][j] = *(const bf16x8*)&lB[bb_ + j * 1024 + co_];            \
  }

#define G8(MQ, NQ, KS)                                                        \
  __builtin_amdgcn_s_setprio(1);                                              \
  _Pragma("unroll") for (int i = 0; i < 4; ++i)                               \
  _Pragma("unroll") for (int j = 0; j < 2; ++j)                               \
      acc[(MQ)*4 + i][(NQ)*2 + j] = __builtin_amdgcn_mfma_f32_16x16x32_bf16(  \
          fa[MQ][KS][i], fb[NQ][KS][j], acc[(MQ)*4 + i][(NQ)*2 + j], 0, 0, 0);\
  __builtin_amdgcn_s_setprio(0);

// One K-tile, parity P = T&1. Gray order (0,0),(0,1),(1,1),(1,0); in-place
// refills: fa[0] after its last consumer g3, fb[1] after g5, fb[0]+fa[1]
// after g7 (tail reads drained by the explicit lgkmcnt(0)).
#define TILE_BODY(P, T)                                                       \
  {                                                                           \
    const bool s1_ = (T) + 1 < nt, s2_ = (T) + 2 < nt;                        \
    if (s2_) {                                                                \
      stageA(P, 0, (T) + 2); stageA(P, 1, (T) + 2);                           \
      stageB(P, 0, (T) + 2); stageB(P, 1, (T) + 2);                           \
    }                                                                         \
    G8(0, 0, 0); G8(0, 0, 1); G8(0, 1, 0); G8(0, 1, 1);                       \
    if (s1_) { LDA4((P) ^ 1, 0, 0); LDA4((P) ^ 1, 0, 1); }                    \
    G8(1, 1, 0); G8(1, 1, 1);                                                 \
    if (s1_) { LDB2((P) ^ 1, 1, 0); LDB2((P) ^ 1, 1, 1); }                    \
    G8(1, 0, 0); G8(1, 0, 1);                                                 \
    if (s1_) {                                                                \
      LDB2((P) ^ 1, 0, 0); LDB2((P) ^ 1, 0, 1);                               \
      LDA4((P) ^ 1, 1, 0); LDA4((P) ^ 1, 1, 1);                               \
      lgkm0(); vm_wait<0>(); bar();                                           \
    }                                                                         \
  }

template <int MODE>
__global__ __launch_bounds__(512, 2) void gemm_kernel(
    const bf16* __restrict__ A, const bf16* __restrict__ B,
    const float* __restrict__ bias, void* __restrict__ Cv,
    const bf16* __restrict__ addb, int K, int ldc, int coloff, int addld,
    int nby) {
  __shared__ bf16 lA[32768];  // [buf][unit][128][64]
  __shared__ bf16 lB[32768];

  // T1: XCD-aware block swizzle (all grids here are multiples of 8)
  const int nwg = gridDim.x;
  int bid = blockIdx.x;
  if ((nwg & 7) == 0) bid = (bid & 7) * (nwg >> 3) + (bid >> 3);
  const int m0 = (bid % nby) * 256;
  const int n0 = (bid / nby) * 256;

  const int tid = threadIdx.x;
  const int wv = tid >> 6, ln = tid & 63;
  const int wm = wv >> 2, wn = wv & 3;  // 2x4 waves, each 128x64 of C

  // staging lane geometry: lane covers row (wv*8 + ln>>3), slot (ln&7),
  // fetching logical chunk (ln&7)^(ln>>3)  [pre-swizzled source]
  const int rowq = wv * 8 + (ln >> 3);
  const int colo = ((ln & 7) ^ (ln >> 3)) * 8;
  const bf16* gA = A + (size_t)(m0 + rowq) * K + colo;
  const bf16* gB = B + (size_t)(n0 + rowq) * K + colo;

  auto stageA = [&](int bf, int u, int t) {
#pragma unroll
    for (int r = 0; r < 2; ++r)
      async_ld16(gA + (size_t)(r * 128 + u * 64) * K + t * 64,
                 &lA[((bf * 2 + u) * 128 + r * 64 + wv * 8) * 64]);
  };
  auto stageB = [&](int bf, int u, int t) {
#pragma unroll
    for (int r = 0; r < 2; ++r)
      async_ld16(gB + (size_t)(r * 128 + u * 64) * K + t * 64,
                 &lB[((bf * 2 + u) * 128 + r * 64 + wv * 8) * 64]);
  };

  // fragment read geometry (16x16x32: A row = ln&15, k-chunk = ln>>4)
  const int l15 = ln & 15;
  const int aOff = (wm * 64 + l15) * 64;  // unit-local row * 64
  const int bOff = (wn * 32 + l15) * 64;
  const int c0 = (ln >> 4) ^ (ln & 7);    // swizzled chunk slot, ks=0

  f32x4 acc[8][4] = {};
  bf16x8 fa[2][2][4];  // [MQ][ks][i]
  bf16x8 fb[2][2][2];  // [NQ][ks][j]

  const int nt = K >> 6;  // all K here: 512/1024/1536/2048 -> nt even, >=8

  // prologue: stage tiles 0 and 1 fully; hard-retire both (loads only);
  // fill F(tile0) from buf0; drain; barrier (so tile0's stage(2->buf0) is
  // >=1 barrier after these reads).
  stageA(0, 0, 0); stageA(0, 1, 0); stageB(0, 0, 0); stageB(0, 1, 0);
  stageA(1, 0, 1); stageA(1, 1, 1); stageB(1, 0, 1); stageB(1, 1, 1);
  vm_wait<0>();
  bar();
  LDA4(0, 0, 0); LDA4(0, 0, 1); LDA4(0, 1, 0); LDA4(0, 1, 1);
  LDB2(0, 0, 0); LDB2(0, 0, 1); LDB2(0, 1, 0); LDB2(0, 1, 1);
  lgkm0();
  bar();

  for (int t = 0; t < nt; t += 2) {
    TILE_BODY(0, t);
    TILE_BODY(1, t + 1);
  }

  // epilogue: 16x16 C/D layout col = ln&15, row = (ln>>4)*4 + r.
  // Column base must match the B fragment-read mapping (see header comment).
  const int r4 = (ln >> 4) * 4;
  const int nbase = n0 + (wn >> 1) * 128 + (wn & 1) * 32 + l15;
#pragma unroll
  for (int mi = 0; mi < 8; ++mi) {
#pragma unroll
    for (int ni = 0; ni < 4; ++ni) {
#pragma unroll
      for (int r = 0; r < 4; ++r) {
        const int m = m0 + wm * 128 + mi * 16 + r4 + r;
        const int n = nbase + (ni >> 1) * 64 + (ni & 1) * 16;
        float v = acc[mi][ni][r];
        if constexpr (MODE != 3) v += bias[n];
        if constexpr (MODE == 0) {
          ((bf16*)Cv)[(size_t)m * ldc + n] = (bf16)v;
        } else if constexpr (MODE == 1) {
          float prev = (float)addb[(size_t)m * addld + n];
          ((bf16*)Cv)[(size_t)m * ldc + n] = (bf16)(prev + fmaxf(v, 0.f));
        } else if constexpr (MODE == 2) {
          v += (float)addb[(size_t)m * addld + n];
          ((bf16*)Cv)[(size_t)m * ldc + coloff + n] = (bf16)v;
        } else {
          float* C = (float*)Cv;
          const size_t idx = (size_t)m * ldc + n;
          C[idx] = C[idx] + v;
        }
      }
    }
  }
}

template <int MODE>
static void launch_gemm(hipStream_t s, const bf16* A, const bf16* B,
                        const float* bias, void* C, const bf16* addb, int M,
                        int N, int K, int ldc, int coloff, int addld) {
  const int nby = M / 256;
  gemm_kernel<MODE><<<dim3((N / 256) * nby), 512, 0, s>>>(
      A, B, bias, C, addb, K, ldc, coloff, addld, nby);
}

// ---------------------------------------------------------------------------
// fp32 [K,N] -> bf16 [N,K] transpose-convert, 32x32 tiles, batched over z
__global__ void transpose_cvt(const float* __restrict__ src,
                              bf16* __restrict__ dst, int K, int N) {
  __shared__ float t[32][33];
  const size_t zo = (size_t)blockIdx.z * K * N;
  src += zo;
  dst += zo;
  const int n = blockIdx.x * 32 + threadIdx.x;
  const int kb = blockIdx.y * 32;
#pragma unroll
  for (int i = 0; i < 4; ++i) {
    const int k = kb + threadIdx.y + i * 8;
    t[threadIdx.y + i * 8][threadIdx.x] = src[(size_t)k * N + n];
  }
  __syncthreads();
#pragma unroll
  for (int i = 0; i < 4; ++i) {
    const int nn = blockIdx.x * 32 + threadIdx.y + i * 8;
    dst[(size_t)nn * K + kb + threadIdx.x] =
        (bf16)t[threadIdx.x][threadIdx.y + i * 8];
  }
}

// ---------------------------------------------------------------------------
// Q = normalize(h)[src], K = rep[dst]; emit bf16 Q,K and fp32 (Q-K) -> d_out
__global__ __launch_bounds__(256) void gather_kernel(
    const float* __restrict__ h, const float* __restrict__ rep,
    const int* __restrict__ src, const int* __restrict__ dst,
    bf16* __restrict__ Qb, bf16* __restrict__ Kb, float* __restrict__ qk) {
  __shared__ float sm[4];
  const int e = blockIdx.x, tid = threadIdx.x;
  const int sr = src[e], dr = dst[e];
  const float4 hv = ((const float4*)(h + (size_t)sr * ND))[tid];
  float ss = hv.x * hv.x + hv.y * hv.y + hv.z * hv.z + hv.w * hv.w;
#pragma unroll
  for (int o = 32; o > 0; o >>= 1) ss += __shfl_down(ss, o, 64);
  if ((tid & 63) == 0) sm[tid >> 6] = ss;
  __syncthreads();
  const float tot = sm[0] + sm[1] + sm[2] + sm[3];
  const float inv = 1.f / fmaxf(sqrtf(tot), 1e-12f);
  const float4 rv = ((const float4*)(rep + (size_t)dr * ND))[tid];
  const float q0 = hv.x * inv, q1 = hv.y * inv, q2 = hv.z * inv,
              q3 = hv.w * inv;
  const size_t base = (size_t)e * ND + tid * 4;
  bf16x4 qv;
  qv[0] = (bf16)q0; qv[1] = (bf16)q1; qv[2] = (bf16)q2; qv[3] = (bf16)q3;
  *(bf16x4*)(Qb + base) = qv;
  bf16x4 kv;
  kv[0] = (bf16)rv.x; kv[1] = (bf16)rv.y; kv[2] = (bf16)rv.z;
  kv[3] = (bf16)rv.w;
  *(bf16x4*)(Kb + base) = kv;
  *(float4*)(qk + base) =
      make_float4(q0 - rv.x, q1 - rv.y, q2 - rv.z, q3 - rv.w);
}

// ---------------------------------------------------------------------------
// attn = softmax(Qp*Kp/sqrt(A), axis=-1) * Vp   (per row of 512)
// Qp/Kp/Vp are [E][H*A]; attn out is [h][E][A]. grid = (E, H).
__global__ __launch_bounds__(256) void softmax_kernel(
    const bf16* __restrict__ Qp, const bf16* __restrict__ Kp,
    const bf16* __restrict__ Vp, bf16* __restrict__ attn) {
  __shared__ float sm[4];
  const int tid = threadIdx.x;
  const int e = blockIdx.x, hh = blockIdx.y;
  const size_t base = (size_t)e * (NH * NA) + (size_t)hh * NA + 2 * tid;
  const bf16x2 q = *(const bf16x2*)(Qp + base);
  const bf16x2 k = *(const bf16x2*)(Kp + base);
  const bf16x2 v = *(const bf16x2*)(Vp + base);
  const float sc = 0.044194173824159216f;  // 1/sqrt(512)
  const float s0 = (float)q[0] * (float)k[0] * sc;
  const float s1 = (float)q[1] * (float)k[1] * sc;
  float mx = fmaxf(s0, s1);
#pragma unroll
  for (int o = 32; o > 0; o >>= 1) mx = fmaxf(mx, __shfl_down(mx, o, 64));
  if ((tid & 63) == 0) sm[tid >> 6] = mx;
  __syncthreads();
  mx = fmaxf(fmaxf(sm[0], sm[1]), fmaxf(sm[2], sm[3]));
  __syncthreads();
  const float p0 = expf(s0 - mx), p1 = expf(s1 - mx);
  float ssum = p0 + p1;
#pragma unroll
  for (int o = 32; o > 0; o >>= 1) ssum += __shfl_down(ssum, o, 64);
  if ((tid & 63) == 0) sm[tid >> 6] = ssum;
  __syncthreads();
  const float inv = 1.f / (sm[0] + sm[1] + sm[2] + sm[3]);
  bf16x2 r;
  r[0] = (bf16)(p0 * inv * (float)v[0]);
  r[1] = (bf16)(p1 * inv * (float)v[1]);
  const size_t obase = (size_t)hh * NE * NA + (size_t)e * NA + 2 * tid;
  *(bf16x2*)(attn + obase) = r;
}

// ---------------------------------------------------------------------------
// y = LN(x) * g + b over rows of 2048
__global__ __launch_bounds__(256) void ln_kernel(const bf16* __restrict__ x,
                                                 bf16* __restrict__ y,
                                                 const float* __restrict__ g,
                                                 const float* __restrict__ b) {
  __shared__ float sm[8];
  const int tid = threadIdx.x;
  const size_t base = (size_t)blockIdx.x * NM + tid * 8;
  const bf16x8 xv = *(const bf16x8*)(x + base);
  float xf[8], s = 0.f, ss = 0.f;
#pragma unroll
  for (int i = 0; i < 8; ++i) {
    xf[i] = (float)xv[i];
    s += xf[i];
    ss += xf[i] * xf[i];
  }
#pragma unroll
  for (int o = 32; o > 0; o >>= 1) {
    s += __shfl_down(s, o, 64);
    ss += __shfl_down(ss, o, 64);
  }
  if ((tid & 63) == 0) {
    sm[tid >> 6] = s;
    sm[4 + (tid >> 6)] = ss;
  }
  __syncthreads();
  s = sm[0] + sm[1] + sm[2] + sm[3];
  ss = sm[4] + sm[5] + sm[6] + sm[7];
  const float mu = s * (1.f / NM);
  const float var = ss * (1.f / NM) - mu * mu;
  const float rstd = rsqrtf(fmaxf(var, 0.f) + 1e-5f);
  const int c0 = tid * 8;
  bf16x8 yv;
#pragma unroll
  for (int i = 0; i < 8; ++i)
    yv[i] = (bf16)((xf[i] - mu) * rstd * g[c0 + i] + b[c0 + i]);
  *(bf16x8*)(y + base) = yv;
}

// ---------------------------------------------------------------------------
extern "C" void kernel_launch(void* const* d_in, const int* in_sizes, int n_in,
                              void* d_out, int out_size, void* d_ws,
                              size_t ws_size, hipStream_t stream) {
  const float* h    = (const float*)d_in[0];
  const float* rep  = (const float*)d_in[1];
  const int* src    = (const int*)d_in[2];
  const int* dst    = (const int*)d_in[3];
  const float* Wq   = (const float*)d_in[4];
  const float* bq   = (const float*)d_in[5];
  const float* Wk   = (const float*)d_in[6];
  const float* bk   = (const float*)d_in[7];
  const float* Wv   = (const float*)d_in[8];
  const float* bv   = (const float*)d_in[9];
  const float* W0   = (const float*)d_in[10];
  const float* b0   = (const float*)d_in[11];
  const float* Wr   = (const float*)d_in[12];
  const float* br   = (const float*)d_in[13];
  const float* g_ln = (const float*)d_in[14];
  const float* b_ln = (const float*)d_in[15];
  const float* Wms  = (const float*)d_in[16];
  const float* bms  = (const float*)d_in[17];
  const float* Wuas = (const float*)d_in[18];
  float* out = (float*)d_out;

  bf16* ws = (bf16*)d_ws;
  size_t off = 0;
  auto alloc = [&](size_t n) {
    bf16* p = ws + off;
    off += n;
    return p;
  };
  bf16* WqT   = alloc((size_t)NH * NA * ND);       // [h*512][1024] = [1536][1024]
  bf16* WkT   = alloc((size_t)NH * NA * ND);
  bf16* WvT   = alloc((size_t)NH * NA * ND);
  bf16* W0T   = alloc((size_t)NH * NM * NA);       // [h][2048][512]
  bf16* WrT   = alloc((size_t)NH * NRES * NM * NM);// [h*3+j][2048][2048]
  bf16* WmsT  = alloc((size_t)NH * NA * NM);       // [h][512][2048]
  bf16* WuasT = alloc((size_t)ND * NH * NA);       // [1024][1536]
  bf16* Qb    = alloc((size_t)NE * ND);
  bf16* Kb    = alloc((size_t)NE * ND);
  bf16* Qp    = alloc((size_t)NE * NH * NA);       // [E][1536]; later reused as cat
  bf16* Kp    = alloc((size_t)NE * NH * NA);
  bf16* Vp    = alloc((size_t)NE * NH * NA);
  bf16* attn  = alloc((size_t)NH * NE * NA);       // [h][E][512]
  bf16* mbuf  = alloc((size_t)NE * NM);
  bf16* xnb   = alloc((size_t)NE * NM);
  bf16* cat   = Qp;                                // alias: Qp dead after softmax
  if (ws_size < off * sizeof(bf16)) return;  // workspace too small: bail

  const dim3 tb(32, 8);
  transpose_cvt<<<dim3(NA / 32, ND / 32, NH), tb, 0, stream>>>(Wq, WqT, ND, NA);
  transpose_cvt<<<dim3(NA / 32, ND / 32, NH), tb, 0, stream>>>(Wk, WkT, ND, NA);
  transpose_cvt<<<dim3(NA / 32, ND / 32, NH), tb, 0, stream>>>(Wv, WvT, ND, NA);
  transpose_cvt<<<dim3(NM / 32, NA / 32, NH), tb, 0, stream>>>(W0, W0T, NA, NM);
  transpose_cvt<<<dim3(NM / 32, NM / 32, NH * NRES), tb, 0, stream>>>(Wr, WrT,
                                                                      NM, NM);
  transpose_cvt<<<dim3(NA / 32, NM / 32, NH), tb, 0, stream>>>(Wms, WmsT, NM,
                                                               NA);
  transpose_cvt<<<dim3(ND / 32, (NH * NA) / 32, 1), tb, 0, stream>>>(
      Wuas, WuasT, NH * NA, ND);

  gather_kernel<<<NE, 256, 0, stream>>>(h, rep, src, dst, Qb, Kb, out);

  // fused QKV projections: N = H*A = 1536
  launch_gemm<0>(stream, Qb, WqT, bq, Qp, nullptr, NE, NH * NA, ND, NH * NA,
                 0, 0);
  launch_gemm<0>(stream, Kb, WkT, bk, Kp, nullptr, NE, NH * NA, ND, NH * NA,
                 0, 0);
  launch_gemm<0>(stream, Kb, WvT, bv, Vp, nullptr, NE, NH * NA, ND, NH * NA,
                 0, 0);
  softmax_kernel<<<dim3(NE, NH), 256, 0, stream>>>(Qp, Kp, Vp, attn);

  for (int hh = 0; hh < NH; ++hh) {
    const bf16* attn_h = attn + (size_t)hh * NE * NA;
    launch_gemm<0>(stream, attn_h, W0T + (size_t)hh * NM * NA, b0 + hh * NM,
                   mbuf, nullptr, NE, NM, NA, NM, 0, 0);
    for (int j = 0; j < NRES; ++j) {
      const int hj = hh * NRES + j;
      ln_kernel<<<NE, 256, 0, stream>>>(mbuf, xnb, g_ln + (size_t)hj * NM,
                                        b_ln + (size_t)hj * NM);
      launch_gemm<1>(stream, xnb, WrT + (size_t)hj * NM * NM, br + hj * NM,
                     mbuf, mbuf, NE, NM, NM, NM, 0, NM);
    }
    launch_gemm<2>(stream, mbuf, WmsT + (size_t)hh * NA * NM, bms + hh * NA,
                   cat, attn_h, NE, NA, NM, NH * NA, hh * NA, NA);
  }
  launch_gemm<3>(stream, cat, WuasT, nullptr, out, nullptr, NE, ND, NH * NA,
                 ND, 0, 0);
}

// Round 7
// 2722.989 us; speedup vs baseline: 2.0783x; 2.0783x over previous
//
#include <hip/hip_runtime.h>
#include <hip/hip_bf16.h>
#include <cstdint>
#include <cstddef>

typedef __bf16 bf16;
typedef __bf16 bf16x2 __attribute__((ext_vector_type(2)));
typedef __bf16 bf16x4 __attribute__((ext_vector_type(4)));
typedef __bf16 bf16x8 __attribute__((ext_vector_type(8)));
typedef float f32x4 __attribute__((ext_vector_type(4)));

static_assert(sizeof(bf16x8) == 16, "bf16x8 must be 16B");

#define NE 16384   // E
#define ND 1024    // D
#define NA 512     // A
#define NM 2048    // M
#define NH 3
#define NRES 3

// ---------------------------------------------------------------------------
// async global->LDS, 16B per lane (wave-uniform LDS base + lane*16 implicit)
__device__ __forceinline__ void async_ld16(const bf16* g, bf16* l) {
  __builtin_amdgcn_global_load_lds(
      (__attribute__((address_space(1))) void*)(void*)g,
      (__attribute__((address_space(3))) void*)(void*)l, 16, 0, 0);
}

template <int N>
__device__ __forceinline__ void vm_wait() {
  asm volatile("s_waitcnt vmcnt(%0)" ::"n"(N) : "memory");
}
__device__ __forceinline__ void lgkm0() {
  asm volatile("s_waitcnt lgkmcnt(0)" ::: "memory");
}
__device__ __forceinline__ void bar() {
  asm volatile("s_barrier" ::: "memory");
}

// ---------------------------------------------------------------------------
// 256x256-tile bf16 GEMM, 3-barriers-per-K-tile: C = A[M,K] @ B^T[N,K], fp32
// accum via v_mfma_f32_16x16x32_bf16. 512 threads = 8 waves (2M x 4N), each
// wave owns 128x64 of C (acc[8][4] f32x4). K in 64-wide tiles.
//
// R7 = R5's register scheme (fa[2][4] ping-pong + fb0/fb1; 24 ds_read_b128 /
// wave / tile; ~116 VGPR, no spill — R6's full-double-set spilled: WRITE_SIZE
// 66->314MB) with the MINIMUM barrier set (3/tile vs R5's 8):
//   barA: after fb1 + fa-MQ1 reads drain (lgkm0)  -> legalizes staging
//         units[1] (Bh1,Ah1 of t+2)
//   barB: after counted vm_wait<8> (retires ALL of tile t+1, issued during
//         t-1; leaves t+2's 8 in flight)          -> publishes t+1 for the
//         prefetch reads (fb0',fa0')
//   barC: after prefetch reads drain (lgkm0)      -> legalizes next tile's
//         units[0] staging (Bh0,Ah0 of t+3)
// Hazard ledger (stage >= 1 bar after its region's drained reads):
//   Bh0/Ah0(t+2)@tile-start -> units[0]: last reads = prefetch @ t-1 Half2b,
//     drained by t-1's lgkm0+barC.
//   Bh1/Ah1(t+2)@Half2a -> units[1]: last reads = fb1/fa-MQ1 @ t Half1,
//     drained by Half1's lgkm0+barA.
//   prefetch reads @ Half2b <- buf-nb: t+1 stages retired by all-waves
//     vm_wait<8> + barB.
//
// LDS per matrix: [2 bufs][2 units][128 rows][64 cols] bf16 (64 KiB), total
// 128 KiB. Unit u holds global rows (lr>>6)*128 + u*64 + (lr&63). Chunk
// swizzle: logical chunk cc of row r stored at slot cc ^ (r&7); global source
// pre-swizzled so global_load_lds dest stays linear.
//
// Block mapping (R7): n-index = bid%nbx so each XCD's resident window = few
// m-panels (A L2-resident) x all n (B shared) -> cuts A re-fetch.
//
// C-column mapping: n = (wn>>1)*128 + NQ*64 + (wn&1)*32 + j*16 + l15
//
// MODE 0: C_bf16 = acc + bias[n]
// MODE 1: C_bf16 = addb[m,n] + relu(acc + bias[n])        (residual, in-place)
// MODE 2: C_bf16[m, coloff+n] = acc + bias[n] + addb[m,n] (head_out -> cat)
// MODE 3: C_f32[m,n] += acc                               (final += Q-K)

#define LDA_H(KS, BUF, MQ)                                                    \
  {                                                                           \
    const int ab_ = ((BUF)*2 + (MQ)) * 8192 + aOff;                           \
    const int co_ = (c0 ^ ((KS) << 2)) * 8;                                   \
    _Pragma("unroll") for (int i = 0; i < 4; ++i)                             \
        fa[KS][i] = *(const bf16x8*)&lA[ab_ + i * 1024 + co_];                \
  }

#define LDB_H(DST, KS, BUF, NQ)                                               \
  {                                                                           \
    const int bb_ = ((BUF)*2 + (NQ)) * 8192 + bOff;                           \
    const int co_ = (c0 ^ ((KS) << 2)) * 8;                                   \
    _Pragma("unroll") for (int j = 0; j < 2; ++j)                             \
        DST[KS][j] = *(const bf16x8*)&lB[bb_ + j * 1024 + co_];               \
  }

#define MFMA_H(KS, MQ, NQ, FB)                                                \
  __builtin_amdgcn_s_setprio(1);                                              \
  _Pragma("unroll") for (int i = 0; i < 4; ++i)                               \
  _Pragma("unroll") for (int j = 0; j < 2; ++j)                               \
      acc[(MQ)*4 + i][(NQ)*2 + j] = __builtin_amdgcn_mfma_f32_16x16x32_bf16(  \
          fa[KS][i], FB[KS][j], acc[(MQ)*4 + i][(NQ)*2 + j], 0, 0, 0);        \
  __builtin_amdgcn_s_setprio(0);

template <int MODE>
__global__ __launch_bounds__(512, 2) void gemm_kernel(
    const bf16* __restrict__ A, const bf16* __restrict__ B,
    const float* __restrict__ bias, void* __restrict__ Cv,
    const bf16* __restrict__ addb, int K, int ldc, int coloff, int addld,
    int nbx) {
  __shared__ bf16 lA[32768];  // [buf][unit][128][64]
  __shared__ bf16 lB[32768];

  // T1: XCD-aware block swizzle (all grids here are multiples of 8)
  const int nwg = gridDim.x;
  int bid = blockIdx.x;
  if ((nwg & 7) == 0) bid = (bid & 7) * (nwg >> 3) + (bid >> 3);
  const int n0 = (bid % nbx) * 256;
  const int m0 = (bid / nbx) * 256;

  const int tid = threadIdx.x;
  const int wv = tid >> 6, ln = tid & 63;
  const int wm = wv >> 2, wn = wv & 3;  // 2x4 waves, each 128x64 of C

  // staging lane geometry: lane covers row (wv*8 + ln>>3), slot (ln&7),
  // fetching logical chunk (ln&7)^(ln>>3)  [pre-swizzled source]
  const int rowq = wv * 8 + (ln >> 3);
  const int colo = ((ln & 7) ^ (ln >> 3)) * 8;
  const bf16* gA = A + (size_t)(m0 + rowq) * K + colo;
  const bf16* gB = B + (size_t)(n0 + rowq) * K + colo;

  auto stageA = [&](int bf, int u, int t) {
#pragma unroll
    for (int r = 0; r < 2; ++r)
      async_ld16(gA + (size_t)(r * 128 + u * 64) * K + t * 64,
                 &lA[((bf * 2 + u) * 128 + r * 64 + wv * 8) * 64]);
  };
  auto stageB = [&](int bf, int u, int t) {
#pragma unroll
    for (int r = 0; r < 2; ++r)
      async_ld16(gB + (size_t)(r * 128 + u * 64) * K + t * 64,
                 &lB[((bf * 2 + u) * 128 + r * 64 + wv * 8) * 64]);
  };

  // fragment read geometry (16x16x32: A row = ln&15, k-chunk = ln>>4)
  const int l15 = ln & 15;
  const int aOff = (wm * 64 + l15) * 64;  // unit-local row * 64
  const int bOff = (wn * 32 + l15) * 64;
  const int c0 = (ln >> 4) ^ (ln & 7);    // swizzled chunk slot, ks=0

  f32x4 acc[8][4] = {};
  bf16x8 fa[2][4], fb0[2][2], fb1[2][2];

  const int nt = K >> 6;  // all K here: 512..2048 -> nt in {8,16,24,32}

  // prologue: stage tiles 0 and 1 fully; vm_wait<8> retires tile 0 (leaves
  // tile 1's 8 in flight); prefetch F(0)'s leading frags (fa-MQ0, fb0);
  // lgkm0+bar so tile0's unit[0] staging is >=1 bar after these reads.
  stageA(0, 0, 0); stageA(0, 1, 0); stageB(0, 0, 0); stageB(0, 1, 0);
  stageA(1, 0, 1); stageA(1, 1, 1); stageB(1, 0, 1); stageB(1, 1, 1);
  vm_wait<8>();
  bar();
  LDA_H(0, 0, 0); LDA_H(1, 0, 0); LDB_H(fb0, 0, 0, 0); LDB_H(fb0, 1, 0, 0);
  lgkm0();
  bar();

  for (int t = 0; t < nt; ++t) {
    const int buf = t & 1, nb = buf ^ 1;
    const bool s1 = t + 1 < nt, s2 = t + 2 < nt;
    // ---- Half1: quadrants (0,0),(0,1) ----
    if (s2) { stageB(buf, 0, t + 2); stageA(buf, 0, t + 2); }
    LDB_H(fb1, 0, buf, 1); LDB_H(fb1, 1, buf, 1);
    MFMA_H(0, 0, 0, fb0);
    MFMA_H(1, 0, 0, fb0);
    MFMA_H(0, 0, 1, fb1);
    LDA_H(0, buf, 1);            // fa[0] <- MQ1-ks0 (MQ0-ks0 dead)
    MFMA_H(1, 0, 1, fb1);
    LDA_H(1, buf, 1);            // fa[1] <- MQ1-ks1
    lgkm0();
    bar();                        // barA
    // ---- Half2a: quadrant (1,1); stage units[1]; retire t+1 ----
    if (s2) { stageB(buf, 1, t + 2); stageA(buf, 1, t + 2); }
    MFMA_H(0, 1, 1, fb1);
    MFMA_H(1, 1, 1, fb1);
    if (s2) { vm_wait<8>(); } else if (s1) { vm_wait<0>(); }
    bar();                        // barB (publishes tile t+1)
    // ---- Half2b: quadrant (1,0); prefetch F(t+1) leading frags ----
    MFMA_H(0, 1, 0, fb0);
    if (s1) { LDB_H(fb0, 0, nb, 0); LDA_H(0, nb, 0); }
    MFMA_H(1, 1, 0, fb0);
    if (s1) { LDB_H(fb0, 1, nb, 0); LDA_H(1, nb, 0); }
    lgkm0();
    bar();                        // barC
  }

  // epilogue: 16x16 C/D layout col = ln&15, row = (ln>>4)*4 + r.
  // Column base must match the B fragment-read mapping (see header comment).
  const int r4 = (ln >> 4) * 4;
  const int nbase = n0 + (wn >> 1) * 128 + (wn & 1) * 32 + l15;
#pragma unroll
  for (int mi = 0; mi < 8; ++mi) {
#pragma unroll
    for (int ni = 0; ni < 4; ++ni) {
#pragma unroll
      for (int r = 0; r < 4; ++r) {
        const int m = m0 + wm * 128 + mi * 16 + r4 + r;
        const int n = nbase + (ni >> 1) * 64 + (ni & 1) * 16;
        float v = acc[mi][ni][r];
        if constexpr (MODE != 3) v += bias[n];
        if constexpr (MODE == 0) {
          ((bf16*)Cv)[(size_t)m * ldc + n] = (bf16)v;
        } else if constexpr (MODE == 1) {
          float prev = (float)addb[(size_t)m * addld + n];
          ((bf16*)Cv)[(size_t)m * ldc + n] = (bf16)(prev + fmaxf(v, 0.f));
        } else if constexpr (MODE == 2) {
          v += (float)addb[(size_t)m * addld + n];
          ((bf16*)Cv)[(size_t)m * ldc + coloff + n] = (bf16)v;
        } else {
          float* C = (float*)Cv;
          const size_t idx = (size_t)m * ldc + n;
          C[idx] = C[idx] + v;
        }
      }
    }
  }
}

template <int MODE>
static void launch_gemm(hipStream_t s, const bf16* A, const bf16* B,
                        const float* bias, void* C, const bf16* addb, int M,
                        int N, int K, int ldc, int coloff, int addld) {
  const int nbx = N / 256;
  gemm_kernel<MODE><<<dim3(nbx * (M / 256)), 512, 0, s>>>(
      A, B, bias, C, addb, K, ldc, coloff, addld, nbx);
}

// ---------------------------------------------------------------------------
// fp32 [K,N] -> bf16 [N,K] transpose-convert, 32x32 tiles, batched over z
__global__ void transpose_cvt(const float* __restrict__ src,
                              bf16* __restrict__ dst, int K, int N) {
  __shared__ float t[32][33];
  const size_t zo = (size_t)blockIdx.z * K * N;
  src += zo;
  dst += zo;
  const int n = blockIdx.x * 32 + threadIdx.x;
  const int kb = blockIdx.y * 32;
#pragma unroll
  for (int i = 0; i < 4; ++i) {
    const int k = kb + threadIdx.y + i * 8;
    t[threadIdx.y + i * 8][threadIdx.x] = src[(size_t)k * N + n];
  }
  __syncthreads();
#pragma unroll
  for (int i = 0; i < 4; ++i) {
    const int nn = blockIdx.x * 32 + threadIdx.y + i * 8;
    dst[(size_t)nn * K + kb + threadIdx.x] =
        (bf16)t[threadIdx.x][threadIdx.y + i * 8];
  }
}

// ---------------------------------------------------------------------------
// Q = normalize(h)[src], K = rep[dst]; emit bf16 Q,K and fp32 (Q-K) -> d_out
__global__ __launch_bounds__(256) void gather_kernel(
    const float* __restrict__ h, const float* __restrict__ rep,
    const int* __restrict__ src, const int* __restrict__ dst,
    bf16* __restrict__ Qb, bf16* __restrict__ Kb, float* __restrict__ qk) {
  __shared__ float sm[4];
  const int e = blockIdx.x, tid = threadIdx.x;
  const int sr = src[e], dr = dst[e];
  const float4 hv = ((const float4*)(h + (size_t)sr * ND))[tid];
  float ss = hv.x * hv.x + hv.y * hv.y + hv.z * hv.z + hv.w * hv.w;
#pragma unroll
  for (int o = 32; o > 0; o >>= 1) ss += __shfl_down(ss, o, 64);
  if ((tid & 63) == 0) sm[tid >> 6] = ss;
  __syncthreads();
  const float tot = sm[0] + sm[1] + sm[2] + sm[3];
  const float inv = 1.f / fmaxf(sqrtf(tot), 1e-12f);
  const float4 rv = ((const float4*)(rep + (size_t)dr * ND))[tid];
  const float q0 = hv.x * inv, q1 = hv.y * inv, q2 = hv.z * inv,
              q3 = hv.w * inv;
  const size_t base = (size_t)e * ND + tid * 4;
  bf16x4 qv;
  qv[0] = (bf16)q0; qv[1] = (bf16)q1; qv[2] = (bf16)q2; qv[3] = (bf16)q3;
  *(bf16x4*)(Qb + base) = qv;
  bf16x4 kv;
  kv[0] = (bf16)rv.x; kv[1] = (bf16)rv.y; kv[2] = (bf16)rv.z;
  kv[3] = (bf16)rv.w;
  *(bf16x4*)(Kb + base) = kv;
  *(float4*)(qk + base) =
      make_float4(q0 - rv.x, q1 - rv.y, q2 - rv.z, q3 - rv.w);
}

// ---------------------------------------------------------------------------
// attn = softmax(Qp*Kp/sqrt(A), axis=-1) * Vp   (per row of 512)
// Qp/Kp/Vp are [E][H*A]; attn out is [h][E][A]. grid = (E, H).
__global__ __launch_bounds__(256) void softmax_kernel(
    const bf16* __restrict__ Qp, const bf16* __restrict__ Kp,
    const bf16* __restrict__ Vp, bf16* __restrict__ attn) {
  __shared__ float sm[4];
  const int tid = threadIdx.x;
  const int e = blockIdx.x, hh = blockIdx.y;
  const size_t base = (size_t)e * (NH * NA) + (size_t)hh * NA + 2 * tid;
  const bf16x2 q = *(const bf16x2*)(Qp + base);
  const bf16x2 k = *(const bf16x2*)(Kp + base);
  const bf16x2 v = *(const bf16x2*)(Vp + base);
  const float sc = 0.044194173824159216f;  // 1/sqrt(512)
  const float s0 = (float)q[0] * (float)k[0] * sc;
  const float s1 = (float)q[1] * (float)k[1] * sc;
  float mx = fmaxf(s0, s1);
#pragma unroll
  for (int o = 32; o > 0; o >>= 1) mx = fmaxf(mx, __shfl_down(mx, o, 64));
  if ((tid & 63) == 0) sm[tid >> 6] = mx;
  __syncthreads();
  mx = fmaxf(fmaxf(sm[0], sm[1]), fmaxf(sm[2], sm[3]));
  __syncthreads();
  const float p0 = expf(s0 - mx), p1 = expf(s1 - mx);
  float ssum = p0 + p1;
#pragma unroll
  for (int o = 32; o > 0; o >>= 1) ssum += __shfl_down(ssum, o, 64);
  if ((tid & 63) == 0) sm[tid >> 6] = ssum;
  __syncthreads();
  const float inv = 1.f / (sm[0] + sm[1] + sm[2] + sm[3]);
  bf16x2 r;
  r[0] = (bf16)(p0 * inv * (float)v[0]);
  r[1] = (bf16)(p1 * inv * (float)v[1]);
  const size_t obase = (size_t)hh * NE * NA + (size_t)e * NA + 2 * tid;
  *(bf16x2*)(attn + obase) = r;
}

// ---------------------------------------------------------------------------
// y = LN(x) * g + b over rows of 2048
__global__ __launch_bounds__(256) void ln_kernel(const bf16* __restrict__ x,
                                                 bf16* __restrict__ y,
                                                 const float* __restrict__ g,
                                                 const float* __restrict__ b) {
  __shared__ float sm[8];
  const int tid = threadIdx.x;
  const size_t base = (size_t)blockIdx.x * NM + tid * 8;
  const bf16x8 xv = *(const bf16x8*)(x + base);
  float xf[8], s = 0.f, ss = 0.f;
#pragma unroll
  for (int i = 0; i < 8; ++i) {
    xf[i] = (float)xv[i];
    s += xf[i];
    ss += xf[i] * xf[i];
  }
#pragma unroll
  for (int o = 32; o > 0; o >>= 1) {
    s += __shfl_down(s, o, 64);
    ss += __shfl_down(ss, o, 64);
  }
  if ((tid & 63) == 0) {
    sm[tid >> 6] = s;
    sm[4 + (tid >> 6)] = ss;
  }
  __syncthreads();
  s = sm[0] + sm[1] + sm[2] + sm[3];
  ss = sm[4] + sm[5] + sm[6] + sm[7];
  const float mu = s * (1.f / NM);
  const float var = ss * (1.f / NM) - mu * mu;
  const float rstd = rsqrtf(fmaxf(var, 0.f) + 1e-5f);
  const int c0 = tid * 8;
  bf16x8 yv;
#pragma unroll
  for (int i = 0; i < 8; ++i)
    yv[i] = (bf16)((xf[i] - mu) * rstd * g[c0 + i] + b[c0 + i]);
  *(bf16x8*)(y + base) = yv;
}

// ---------------------------------------------------------------------------
extern "C" void kernel_launch(void* const* d_in, const int* in_sizes, int n_in,
                              void* d_out, int out_size, void* d_ws,
                              size_t ws_size, hipStream_t stream) {
  const float* h    = (const float*)d_in[0];
  const float* rep  = (const float*)d_in[1];
  const int* src    = (const int*)d_in[2];
  const int* dst    = (const int*)d_in[3];
  const float* Wq   = (const float*)d_in[4];
  const float* bq   = (const float*)d_in[5];
  const float* Wk   = (const float*)d_in[6];
  const float* bk   = (const float*)d_in[7];
  const float* Wv   = (const float*)d_in[8];
  const float* bv   = (const float*)d_in[9];
  const float* W0   = (const float*)d_in[10];
  const float* b0   = (const float*)d_in[11];
  const float* Wr   = (const float*)d_in[12];
  const float* br   = (const float*)d_in[13];
  const float* g_ln = (const float*)d_in[14];
  const float* b_ln = (const float*)d_in[15];
  const float* Wms  = (const float*)d_in[16];
  const float* bms  = (const float*)d_in[17];
  const float* Wuas = (const float*)d_in[18];
  float* out = (float*)d_out;

  bf16* ws = (bf16*)d_ws;
  size_t off = 0;
  auto alloc = [&](size_t n) {
    bf16* p = ws + off;
    off += n;
    return p;
  };
  bf16* WqT   = alloc((size_t)NH * NA * ND);       // [h*512][1024] = [1536][1024]
  bf16* WkT   = alloc((size_t)NH * NA * ND);
  bf16* WvT   = alloc((size_t)NH * NA * ND);
  bf16* W0T   = alloc((size_t)NH * NM * NA);       // [h][2048][512]
  bf16* WrT   = alloc((size_t)NH * NRES * NM * NM);// [h*3+j][2048][2048]
  bf16* WmsT  = alloc((size_t)NH * NA * NM);       // [h][512][2048]
  bf16* WuasT = alloc((size_t)ND * NH * NA);       // [1024][1536]
  bf16* Qb    = alloc((size_t)NE * ND);
  bf16* Kb    = alloc((size_t)NE * ND);
  bf16* Qp    = alloc((size_t)NE * NH * NA);       // [E][1536]; later reused as cat
  bf16* Kp    = alloc((size_t)NE * NH * NA);
  bf16* Vp    = alloc((size_t)NE * NH * NA);
  bf16* attn  = alloc((size_t)NH * NE * NA);       // [h][E][512]
  bf16* mbuf  = alloc((size_t)NE * NM);
  bf16* xnb   = alloc((size_t)NE * NM);
  bf16* cat   = Qp;                                // alias: Qp dead after softmax
  if (ws_size < off * sizeof(bf16)) return;  // workspace too small: bail

  const dim3 tb(32, 8);
  transpose_cvt<<<dim3(NA / 32, ND / 32, NH), tb, 0, stream>>>(Wq, WqT, ND, NA);
  transpose_cvt<<<dim3(NA / 32, ND / 32, NH), tb, 0, stream>>>(Wk, WkT, ND, NA);
  transpose_cvt<<<dim3(NA / 32, ND / 32, NH), tb, 0, stream>>>(Wv, WvT, ND, NA);
  transpose_cvt<<<dim3(NM / 32, NA / 32, NH), tb, 0, stream>>>(W0, W0T, NA, NM);
  transpose_cvt<<<dim3(NM / 32, NM / 32, NH * NRES), tb, 0, stream>>>(Wr, WrT,
                                                                      NM, NM);
  transpose_cvt<<<dim3(NA / 32, NM / 32, NH), tb, 0, stream>>>(Wms, WmsT, NM,
                                                               NA);
  transpose_cvt<<<dim3(ND / 32, (NH * NA) / 32, 1), tb, 0, stream>>>(
      Wuas, WuasT, NH * NA, ND);

  gather_kernel<<<NE, 256, 0, stream>>>(h, rep, src, dst, Qb, Kb, out);

  // fused QKV projections: N = H*A = 1536
  launch_gemm<0>(stream, Qb, WqT, bq, Qp, nullptr, NE, NH * NA, ND, NH * NA,
                 0, 0);
  launch_gemm<0>(stream, Kb, WkT, bk, Kp, nullptr, NE, NH * NA, ND, NH * NA,
                 0, 0);
  launch_gemm<0>(stream, Kb, WvT, bv, Vp, nullptr, NE, NH * NA, ND, NH * NA,
                 0, 0);
  softmax_kernel<<<dim3(NE, NH), 256, 0, stream>>>(Qp, Kp, Vp, attn);

  for (int hh = 0; hh < NH; ++hh) {
    const bf16* attn_h = attn + (size_t)hh * NE * NA;
    launch_gemm<0>(stream, attn_h, W0T + (size_t)hh * NM * NA, b0 + hh * NM,
                   mbuf, nullptr, NE, NM, NA, NM, 0, 0);
    for (int j = 0; j < NRES; ++j) {
      const int hj = hh * NRES + j;
      ln_kernel<<<NE, 256, 0, stream>>>(mbuf, xnb, g_ln + (size_t)hj * NM,
                                        b_ln + (size_t)hj * NM);
      launch_gemm<1>(stream, xnb, WrT + (size_t)hj * NM * NM, br + hj * NM,
                     mbuf, mbuf, NE, NM, NM, NM, 0, NM);
    }
    launch_gemm<2>(stream, mbuf, WmsT + (size_t)hh * NA * NM, bms + hh * NA,
                   cat, attn_h, NE, NA, NM, NH * NA, hh * NA, NA);
  }
  launch_gemm<3>(stream, cat, WuasT, nullptr, out, nullptr, NE, ND, NH * NA,
                 ND, 0, 0);
}

// Round 8
// 2692.030 us; speedup vs baseline: 2.1022x; 1.0115x over previous
//
#include <hip/hip_runtime.h>
#include <hip/hip_bf16.h>
#include <cstdint>
#include <cstddef>

typedef __bf16 bf16;
typedef __bf16 bf16x2 __attribute__((ext_vector_type(2)));
typedef __bf16 bf16x4 __attribute__((ext_vector_type(4)));
typedef __bf16 bf16x8 __attribute__((ext_vector_type(8)));
typedef float f32x4 __attribute__((ext_vector_type(4)));

static_assert(sizeof(bf16x8) == 16, "bf16x8 must be 16B");

#define NE 16384   // E
#define ND 1024    // D
#define NA 512     // A
#define NM 2048    // M
#define NH 3
#define NRES 3

// ---------------------------------------------------------------------------
// async global->LDS, 16B per lane (wave-uniform LDS base + lane*16 implicit)
__device__ __forceinline__ void async_ld16(const bf16* g, bf16* l) {
  __builtin_amdgcn_global_load_lds(
      (__attribute__((address_space(1))) void*)(void*)g,
      (__attribute__((address_space(3))) void*)(void*)l, 16, 0, 0);
}

template <int N>
__device__ __forceinline__ void vm_wait() {
  asm volatile("s_waitcnt vmcnt(%0)" ::"n"(N) : "memory");
}
__device__ __forceinline__ void lgkm0() {
  asm volatile("s_waitcnt lgkmcnt(0)" ::: "memory");
}
__device__ __forceinline__ void bar() {
  asm volatile("s_barrier" ::: "memory");
}
#define PIN() __builtin_amdgcn_sched_barrier(0)

// ---------------------------------------------------------------------------
// 256x256-tile bf16 GEMM, 3-barriers-per-K-tile (R7 schedule) + R8 scheduler
// PINNING: R2-R7 all landed at 28-35% MfmaUtil regardless of schedule shape;
// cycle model says LDS and MFMA pipes run serialized (6075 cyc/tile vs ~3300
// overlapped). Hypothesis: at high reg pressure LLVM sinks the mid-MFMA
// ds_read clusters to the tail lgkmcnt(0), emitting [MFMAs][reads][drain].
// Fix: sched_barrier(0) fences around each read/stage cluster so the emitted
// order keeps reads under MFMA execution (light pinning, ~7/tile).
//
// Sync structure (verified R7): 3 barriers/tile —
//   barA after fb1+fa-MQ1 reads drain -> legalizes staging units[1](t+2)
//   barB after counted vm_wait<8> (retires tile t+1; t+2's 8 stay in flight)
//   barC after prefetch reads drain -> legalizes next tile's units[0] staging
//
// LDS per matrix: [2 bufs][2 units][128 rows][64 cols] bf16, 128 KiB total.
// Unit u holds global rows (lr>>6)*128 + u*64 + (lr&63). Chunk swizzle:
// logical chunk cc of row r at slot cc^(r&7); global source pre-swizzled.
// Block mapping: n-major (bid%nbx) -> A panels L2-resident (FETCH 303->131MB).
// C-column mapping: n = (wn>>1)*128 + NQ*64 + (wn&1)*32 + j*16 + l15
//
// MODE 0: C_bf16 = acc + bias[n]; optional split-output: if coloff!=0 and
//         n>=coloff, index += addld (fused K/V projection -> Kp then Vp)
// MODE 1: C_bf16 = addb[m,n] + relu(acc + bias[n])        (residual, in-place)
// MODE 2: C_bf16[m, coloff+n] = acc + bias[n] + addb[m,n] (head_out -> cat)
// MODE 3: C_f32[m,n] += acc                               (final += Q-K)

#define LDA_H(KS, BUF, MQ)                                                    \
  {                                                                           \
    const int ab_ = ((BUF)*2 + (MQ)) * 8192 + aOff;                           \
    const int co_ = (c0 ^ ((KS) << 2)) * 8;                                   \
    _Pragma("unroll") for (int i = 0; i < 4; ++i)                             \
        fa[KS][i] = *(const bf16x8*)&lA[ab_ + i * 1024 + co_];                \
  }

#define LDB_H(DST, KS, BUF, NQ)                                               \
  {                                                                           \
    const int bb_ = ((BUF)*2 + (NQ)) * 8192 + bOff;                           \
    const int co_ = (c0 ^ ((KS) << 2)) * 8;                                   \
    _Pragma("unroll") for (int j = 0; j < 2; ++j)                             \
        DST[KS][j] = *(const bf16x8*)&lB[bb_ + j * 1024 + co_];               \
  }

#define MFMA_H(KS, MQ, NQ, FB)                                                \
  __builtin_amdgcn_s_setprio(1);                                              \
  _Pragma("unroll") for (int i = 0; i < 4; ++i)                               \
  _Pragma("unroll") for (int j = 0; j < 2; ++j)                               \
      acc[(MQ)*4 + i][(NQ)*2 + j] = __builtin_amdgcn_mfma_f32_16x16x32_bf16(  \
          fa[KS][i], FB[KS][j], acc[(MQ)*4 + i][(NQ)*2 + j], 0, 0, 0);        \
  __builtin_amdgcn_s_setprio(0);

template <int MODE>
__global__ __launch_bounds__(512, 2) void gemm_kernel(
    const bf16* __restrict__ A, const bf16* __restrict__ B,
    const float* __restrict__ bias, void* __restrict__ Cv,
    const bf16* __restrict__ addb, int K, int ldc, int coloff, int addld,
    int nbx) {
  __shared__ bf16 lA[32768];  // [buf][unit][128][64]
  __shared__ bf16 lB[32768];

  // T1: XCD-aware block swizzle (all grids here are multiples of 8)
  const int nwg = gridDim.x;
  int bid = blockIdx.x;
  if ((nwg & 7) == 0) bid = (bid & 7) * (nwg >> 3) + (bid >> 3);
  const int n0 = (bid % nbx) * 256;
  const int m0 = (bid / nbx) * 256;

  const int tid = threadIdx.x;
  const int wv = tid >> 6, ln = tid & 63;
  const int wm = wv >> 2, wn = wv & 3;  // 2x4 waves, each 128x64 of C

  // staging lane geometry: lane covers row (wv*8 + ln>>3), slot (ln&7),
  // fetching logical chunk (ln&7)^(ln>>3)  [pre-swizzled source]
  const int rowq = wv * 8 + (ln >> 3);
  const int colo = ((ln & 7) ^ (ln >> 3)) * 8;
  const bf16* gA = A + (size_t)(m0 + rowq) * K + colo;
  const bf16* gB = B + (size_t)(n0 + rowq) * K + colo;

  auto stageA = [&](int bf, int u, int t) {
#pragma unroll
    for (int r = 0; r < 2; ++r)
      async_ld16(gA + (size_t)(r * 128 + u * 64) * K + t * 64,
                 &lA[((bf * 2 + u) * 128 + r * 64 + wv * 8) * 64]);
  };
  auto stageB = [&](int bf, int u, int t) {
#pragma unroll
    for (int r = 0; r < 2; ++r)
      async_ld16(gB + (size_t)(r * 128 + u * 64) * K + t * 64,
                 &lB[((bf * 2 + u) * 128 + r * 64 + wv * 8) * 64]);
  };

  // fragment read geometry (16x16x32: A row = ln&15, k-chunk = ln>>4)
  const int l15 = ln & 15;
  const int aOff = (wm * 64 + l15) * 64;  // unit-local row * 64
  const int bOff = (wn * 32 + l15) * 64;
  const int c0 = (ln >> 4) ^ (ln & 7);    // swizzled chunk slot, ks=0

  f32x4 acc[8][4] = {};
  bf16x8 fa[2][4], fb0[2][2], fb1[2][2];

  const int nt = K >> 6;  // all K here: 512..2048 -> nt in {8,16,24,32,48}

  // prologue: stage tiles 0 and 1 fully; vm_wait<8> retires tile 0 (leaves
  // tile 1's 8 in flight); prefetch F(0)'s leading frags (fa-MQ0, fb0);
  // lgkm0+bar so tile0's unit[0] staging is >=1 bar after these reads.
  stageA(0, 0, 0); stageA(0, 1, 0); stageB(0, 0, 0); stageB(0, 1, 0);
  stageA(1, 0, 1); stageA(1, 1, 1); stageB(1, 0, 1); stageB(1, 1, 1);
  vm_wait<8>();
  bar();
  LDA_H(0, 0, 0); LDA_H(1, 0, 0); LDB_H(fb0, 0, 0, 0); LDB_H(fb0, 1, 0, 0);
  lgkm0();
  bar();

  for (int t = 0; t < nt; ++t) {
    const int buf = t & 1, nb = buf ^ 1;
    const bool s1 = t + 1 < nt, s2 = t + 2 < nt;
    // ---- Half1: quadrants (0,0),(0,1) ----
    if (s2) { stageB(buf, 0, t + 2); stageA(buf, 0, t + 2); }
    PIN();  // stages stay at segment top (no result reg -> sinkable)
    LDB_H(fb1, 0, buf, 1); LDB_H(fb1, 1, buf, 1);
    PIN();  // fb1 reads issued before the fb0 MFMAs
    MFMA_H(0, 0, 0, fb0);
    MFMA_H(1, 0, 0, fb0);
    MFMA_H(0, 0, 1, fb1);
    PIN();
    LDA_H(0, buf, 1);            // fa[0] <- MQ1-ks0 (MQ0-ks0 dead)
    PIN();  // keep this read ahead of g4
    MFMA_H(1, 0, 1, fb1);
    PIN();
    LDA_H(1, buf, 1);            // fa[1] <- MQ1-ks1
    lgkm0();
    bar();                        // barA
    // ---- Half2a: quadrant (1,1); stage units[1]; retire t+1 ----
    if (s2) { stageB(buf, 1, t + 2); stageA(buf, 1, t + 2); }
    PIN();
    MFMA_H(0, 1, 1, fb1);
    MFMA_H(1, 1, 1, fb1);
    if (s2) { vm_wait<8>(); } else if (s1) { vm_wait<0>(); }
    bar();                        // barB (publishes tile t+1)
    // ---- Half2b: quadrant (1,0); prefetch F(t+1) leading frags ----
    MFMA_H(0, 1, 0, fb0);
    PIN();
    if (s1) { LDB_H(fb0, 0, nb, 0); LDA_H(0, nb, 0); }
    PIN();  // prefetch reads issued before g8
    MFMA_H(1, 1, 0, fb0);
    PIN();
    if (s1) { LDB_H(fb0, 1, nb, 0); LDA_H(1, nb, 0); }
    lgkm0();
    bar();                        // barC
  }

  // epilogue: 16x16 C/D layout col = ln&15, row = (ln>>4)*4 + r.
  // Column base must match the B fragment-read mapping (see header comment).
  const int r4 = (ln >> 4) * 4;
  const int nbase = n0 + (wn >> 1) * 128 + (wn & 1) * 32 + l15;
#pragma unroll
  for (int mi = 0; mi < 8; ++mi) {
#pragma unroll
    for (int ni = 0; ni < 4; ++ni) {
#pragma unroll
      for (int r = 0; r < 4; ++r) {
        const int m = m0 + wm * 128 + mi * 16 + r4 + r;
        const int n = nbase + (ni >> 1) * 64 + (ni & 1) * 16;
        float v = acc[mi][ni][r];
        if constexpr (MODE != 3) v += bias[n];
        if constexpr (MODE == 0) {
          size_t idx = (size_t)m * ldc + n;
          if (coloff && n >= coloff) idx += (size_t)addld;  // split output
          ((bf16*)Cv)[idx] = (bf16)v;
        } else if constexpr (MODE == 1) {
          float prev = (float)addb[(size_t)m * addld + n];
          ((bf16*)Cv)[(size_t)m * ldc + n] = (bf16)(prev + fmaxf(v, 0.f));
        } else if constexpr (MODE == 2) {
          v += (float)addb[(size_t)m * addld + n];
          ((bf16*)Cv)[(size_t)m * ldc + coloff + n] = (bf16)v;
        } else {
          float* C = (float*)Cv;
          const size_t idx = (size_t)m * ldc + n;
          C[idx] = C[idx] + v;
        }
      }
    }
  }
}

template <int MODE>
static void launch_gemm(hipStream_t s, const bf16* A, const bf16* B,
                        const float* bias, void* C, const bf16* addb, int M,
                        int N, int K, int ldc, int coloff, int addld) {
  const int nbx = N / 256;
  gemm_kernel<MODE><<<dim3(nbx * (M / 256)), 512, 0, s>>>(
      A, B, bias, C, addb, K, ldc, coloff, addld, nbx);
}

// ---------------------------------------------------------------------------
// fp32 [K,N] -> bf16 [N,K] transpose-convert, 32x32 tiles, batched over z
__global__ void transpose_cvt(const float* __restrict__ src,
                              bf16* __restrict__ dst, int K, int N) {
  __shared__ float t[32][33];
  const size_t zo = (size_t)blockIdx.z * K * N;
  src += zo;
  dst += zo;
  const int n = blockIdx.x * 32 + threadIdx.x;
  const int kb = blockIdx.y * 32;
#pragma unroll
  for (int i = 0; i < 4; ++i) {
    const int k = kb + threadIdx.y + i * 8;
    t[threadIdx.y + i * 8][threadIdx.x] = src[(size_t)k * N + n];
  }
  __syncthreads();
#pragma unroll
  for (int i = 0; i < 4; ++i) {
    const int nn = blockIdx.x * 32 + threadIdx.y + i * 8;
    dst[(size_t)nn * K + kb + threadIdx.x] =
        (bf16)t[threadIdx.x][threadIdx.y + i * 8];
  }
}

// ---------------------------------------------------------------------------
// concat two fp32 vectors (bk|bv) -> dst
__global__ void concat2_kernel(const float* __restrict__ a,
                               const float* __restrict__ b,
                               float* __restrict__ dst, int na) {
  const int i = blockIdx.x * 256 + threadIdx.x;
  dst[i] = (i < na) ? a[i] : b[i - na];
}

// ---------------------------------------------------------------------------
// Q = normalize(h)[src], K = rep[dst]; emit bf16 Q,K and fp32 (Q-K) -> d_out
__global__ __launch_bounds__(256) void gather_kernel(
    const float* __restrict__ h, const float* __restrict__ rep,
    const int* __restrict__ src, const int* __restrict__ dst,
    bf16* __restrict__ Qb, bf16* __restrict__ Kb, float* __restrict__ qk) {
  __shared__ float sm[4];
  const int e = blockIdx.x, tid = threadIdx.x;
  const int sr = src[e], dr = dst[e];
  const float4 hv = ((const float4*)(h + (size_t)sr * ND))[tid];
  float ss = hv.x * hv.x + hv.y * hv.y + hv.z * hv.z + hv.w * hv.w;
#pragma unroll
  for (int o = 32; o > 0; o >>= 1) ss += __shfl_down(ss, o, 64);
  if ((tid & 63) == 0) sm[tid >> 6] = ss;
  __syncthreads();
  const float tot = sm[0] + sm[1] + sm[2] + sm[3];
  const float inv = 1.f / fmaxf(sqrtf(tot), 1e-12f);
  const float4 rv = ((const float4*)(rep + (size_t)dr * ND))[tid];
  const float q0 = hv.x * inv, q1 = hv.y * inv, q2 = hv.z * inv,
              q3 = hv.w * inv;
  const size_t base = (size_t)e * ND + tid * 4;
  bf16x4 qv;
  qv[0] = (bf16)q0; qv[1] = (bf16)q1; qv[2] = (bf16)q2; qv[3] = (bf16)q3;
  *(bf16x4*)(Qb + base) = qv;
  bf16x4 kv;
  kv[0] = (bf16)rv.x; kv[1] = (bf16)rv.y; kv[2] = (bf16)rv.z;
  kv[3] = (bf16)rv.w;
  *(bf16x4*)(Kb + base) = kv;
  *(float4*)(qk + base) =
      make_float4(q0 - rv.x, q1 - rv.y, q2 - rv.z, q3 - rv.w);
}

// ---------------------------------------------------------------------------
// attn = softmax(Qp*Kp/sqrt(A), axis=-1) * Vp   (per row of 512)
// Qp/Kp/Vp are [E][H*A]; attn out is [h][E][A]. grid = (E, H).
__global__ __launch_bounds__(256) void softmax_kernel(
    const bf16* __restrict__ Qp, const bf16* __restrict__ Kp,
    const bf16* __restrict__ Vp, bf16* __restrict__ attn) {
  __shared__ float sm[4];
  const int tid = threadIdx.x;
  const int e = blockIdx.x, hh = blockIdx.y;
  const size_t base = (size_t)e * (NH * NA) + (size_t)hh * NA + 2 * tid;
  const bf16x2 q = *(const bf16x2*)(Qp + base);
  const bf16x2 k = *(const bf16x2*)(Kp + base);
  const bf16x2 v = *(const bf16x2*)(Vp + base);
  const float sc = 0.044194173824159216f;  // 1/sqrt(512)
  const float s0 = (float)q[0] * (float)k[0] * sc;
  const float s1 = (float)q[1] * (float)k[1] * sc;
  float mx = fmaxf(s0, s1);
#pragma unroll
  for (int o = 32; o > 0; o >>= 1) mx = fmaxf(mx, __shfl_down(mx, o, 64));
  if ((tid & 63) == 0) sm[tid >> 6] = mx;
  __syncthreads();
  mx = fmaxf(fmaxf(sm[0], sm[1]), fmaxf(sm[2], sm[3]));
  __syncthreads();
  const float p0 = expf(s0 - mx), p1 = expf(s1 - mx);
  float ssum = p0 + p1;
#pragma unroll
  for (int o = 32; o > 0; o >>= 1) ssum += __shfl_down(ssum, o, 64);
  if ((tid & 63) == 0) sm[tid >> 6] = ssum;
  __syncthreads();
  const float inv = 1.f / (sm[0] + sm[1] + sm[2] + sm[3]);
  bf16x2 r;
  r[0] = (bf16)(p0 * inv * (float)v[0]);
  r[1] = (bf16)(p1 * inv * (float)v[1]);
  const size_t obase = (size_t)hh * NE * NA + (size_t)e * NA + 2 * tid;
  *(bf16x2*)(attn + obase) = r;
}

// ---------------------------------------------------------------------------
// y = LN(x) * g + b over rows of 2048
__global__ __launch_bounds__(256) void ln_kernel(const bf16* __restrict__ x,
                                                 bf16* __restrict__ y,
                                                 const float* __restrict__ g,
                                                 const float* __restrict__ b) {
  __shared__ float sm[8];
  const int tid = threadIdx.x;
  const size_t base = (size_t)blockIdx.x * NM + tid * 8;
  const bf16x8 xv = *(const bf16x8*)(x + base);
  float xf[8], s = 0.f, ss = 0.f;
#pragma unroll
  for (int i = 0; i < 8; ++i) {
    xf[i] = (float)xv[i];
    s += xf[i];
    ss += xf[i] * xf[i];
  }
#pragma unroll
  for (int o = 32; o > 0; o >>= 1) {
    s += __shfl_down(s, o, 64);
    ss += __shfl_down(ss, o, 64);
  }
  if ((tid & 63) == 0) {
    sm[tid >> 6] = s;
    sm[4 + (tid >> 6)] = ss;
  }
  __syncthreads();
  s = sm[0] + sm[1] + sm[2] + sm[3];
  ss = sm[4] + sm[5] + sm[6] + sm[7];
  const float mu = s * (1.f / NM);
  const float var = ss * (1.f / NM) - mu * mu;
  const float rstd = rsqrtf(fmaxf(var, 0.f) + 1e-5f);
  const int c0 = tid * 8;
  bf16x8 yv;
#pragma unroll
  for (int i = 0; i < 8; ++i)
    yv[i] = (bf16)((xf[i] - mu) * rstd * g[c0 + i] + b[c0 + i]);
  *(bf16x8*)(y + base) = yv;
}

// ---------------------------------------------------------------------------
extern "C" void kernel_launch(void* const* d_in, const int* in_sizes, int n_in,
                              void* d_out, int out_size, void* d_ws,
                              size_t ws_size, hipStream_t stream) {
  const float* h    = (const float*)d_in[0];
  const float* rep  = (const float*)d_in[1];
  const int* src    = (const int*)d_in[2];
  const int* dst    = (const int*)d_in[3];
  const float* Wq   = (const float*)d_in[4];
  const float* bq   = (const float*)d_in[5];
  const float* Wk   = (const float*)d_in[6];
  const float* bk   = (const float*)d_in[7];
  const float* Wv   = (const float*)d_in[8];
  const float* bv   = (const float*)d_in[9];
  const float* W0   = (const float*)d_in[10];
  const float* b0   = (const float*)d_in[11];
  const float* Wr   = (const float*)d_in[12];
  const float* br   = (const float*)d_in[13];
  const float* g_ln = (const float*)d_in[14];
  const float* b_ln = (const float*)d_in[15];
  const float* Wms  = (const float*)d_in[16];
  const float* bms  = (const float*)d_in[17];
  const float* Wuas = (const float*)d_in[18];
  float* out = (float*)d_out;

  bf16* ws = (bf16*)d_ws;
  size_t off = 0;
  auto alloc = [&](size_t n) {
    bf16* p = ws + off;
    off += n;
    return p;
  };
  bf16* WqT   = alloc((size_t)NH * NA * ND);       // [h*512][1024] = [1536][1024]
  bf16* WkT   = alloc((size_t)NH * NA * ND);       // contiguous with WvT!
  bf16* WvT   = alloc((size_t)NH * NA * ND);
  bf16* W0T   = alloc((size_t)NH * NM * NA);       // [h][2048][512]
  bf16* WrT   = alloc((size_t)NH * NRES * NM * NM);// [h*3+j][2048][2048]
  bf16* WmsT  = alloc((size_t)NH * NA * NM);       // [h][512][2048]
  bf16* WuasT = alloc((size_t)ND * NH * NA);       // [1024][1536]
  bf16* Qb    = alloc((size_t)NE * ND);
  bf16* Kb    = alloc((size_t)NE * ND);
  bf16* Qp    = alloc((size_t)NE * NH * NA);       // [E][1536]; later reused as cat
  bf16* Kp    = alloc((size_t)NE * NH * NA);       // Kp then Vp contiguous
  bf16* Vp    = alloc((size_t)NE * NH * NA);
  bf16* attn  = alloc((size_t)NH * NE * NA);       // [h][E][512]
  bf16* mbuf  = alloc((size_t)NE * NM);
  bf16* xnb   = alloc((size_t)NE * NM);
  float* cbias = (float*)alloc(2 * (size_t)NH * NA * 2);  // fp32[3072]
  bf16* cat   = Qp;                                // alias: Qp dead after softmax
  if (ws_size < off * sizeof(bf16)) return;  // workspace too small: bail

  const dim3 tb(32, 8);
  transpose_cvt<<<dim3(NA / 32, ND / 32, NH), tb, 0, stream>>>(Wq, WqT, ND, NA);
  transpose_cvt<<<dim3(NA / 32, ND / 32, NH), tb, 0, stream>>>(Wk, WkT, ND, NA);
  transpose_cvt<<<dim3(NA / 32, ND / 32, NH), tb, 0, stream>>>(Wv, WvT, ND, NA);
  transpose_cvt<<<dim3(NM / 32, NA / 32, NH), tb, 0, stream>>>(W0, W0T, NA, NM);
  transpose_cvt<<<dim3(NM / 32, NM / 32, NH * NRES), tb, 0, stream>>>(Wr, WrT,
                                                                      NM, NM);
  transpose_cvt<<<dim3(NA / 32, NM / 32, NH), tb, 0, stream>>>(Wms, WmsT, NM,
                                                               NA);
  transpose_cvt<<<dim3(ND / 32, (NH * NA) / 32, 1), tb, 0, stream>>>(
      Wuas, WuasT, NH * NA, ND);
  concat2_kernel<<<(2 * NH * NA) / 256, 256, 0, stream>>>(bk, bv, cbias,
                                                          NH * NA);

  gather_kernel<<<NE, 256, 0, stream>>>(h, rep, src, dst, Qb, Kb, out);

  // Q projection: N = H*A = 1536
  launch_gemm<0>(stream, Qb, WqT, bq, Qp, nullptr, NE, NH * NA, ND, NH * NA,
                 0, 0);
  // fused K+V projection: N = 3072 (B = [WkT;WvT] contiguous), split output:
  // n<1536 -> Kp[m*1536+n], n>=1536 -> Vp[m*1536+n-1536] = +(NE-1)*1536
  launch_gemm<0>(stream, Kb, WkT, cbias, Kp, nullptr, NE, 2 * NH * NA, ND,
                 NH * NA, NH * NA, (NE - 1) * NH * NA);
  softmax_kernel<<<dim3(NE, NH), 256, 0, stream>>>(Qp, Kp, Vp, attn);

  for (int hh = 0; hh < NH; ++hh) {
    const bf16* attn_h = attn + (size_t)hh * NE * NA;
    launch_gemm<0>(stream, attn_h, W0T + (size_t)hh * NM * NA, b0 + hh * NM,
                   mbuf, nullptr, NE, NM, NA, NM, 0, 0);
    for (int j = 0; j < NRES; ++j) {
      const int hj = hh * NRES + j;
      ln_kernel<<<NE, 256, 0, stream>>>(mbuf, xnb, g_ln + (size_t)hj * NM,
                                        b_ln + (size_t)hj * NM);
      launch_gemm<1>(stream, xnb, WrT + (size_t)hj * NM * NM, br + hj * NM,
                     mbuf, mbuf, NE, NM, NM, NM, 0, NM);
    }
    launch_gemm<2>(stream, mbuf, WmsT + (size_t)hh * NA * NM, bms + hh * NA,
                   cat, attn_h, NE, NA, NM, NH * NA, hh * NA, NA);
  }
  launch_gemm<3>(stream, cat, WuasT, nullptr, out, nullptr, NE, ND, NH * NA,
                 ND, 0, 0);
}